// Round 17
// baseline (188.105 us; speedup 1.0000x reference)
//
#include <hip/hip_runtime.h>
#include <math.h>

#define DDIM 1024
#define HDIM 128

typedef float  f32x4  __attribute__((ext_vector_type(4)));
typedef __bf16 bf16x8 __attribute__((ext_vector_type(8)));

union BF2U { __bf16 h; ushort u; };

__constant__ int c_perms[6][3] = {{0,1,2},{0,2,1},{1,0,2},{1,2,0},{2,0,1},{2,1,0}};

__device__ __forceinline__ ushort f2bf(float f){
    BF2U c; c.h = (__bf16)f; return c.u;
}
// branch-free gelu: A&S 7.1.26 erf (|err| < 1.5e-7), HW exp + raw 1-ulp rcp
__device__ __forceinline__ float gelu_fast(float x){
    float a = fabsf(x) * 0.70710678118654752f;
    float t = __builtin_amdgcn_rcpf(fmaf(0.3275911f, a, 1.0f));
    float p = t * fmaf(t, fmaf(t, fmaf(t, fmaf(t, 1.061405429f, -1.453152027f),
                 1.421413741f), -0.284496736f), 0.254829592f);
    float y = 1.0f - p * __expf(-a * a);
    float er = copysignf(y, x);
    return 0.5f * x * (1.0f + er);
}

// ---------------- K0: weight images (unchanged) ----------------
// w1s: 32 chunks t; halfword i = t*4096 + n*32 + kk = bf16(W1[t*32+kk][n])
//      (BK=64 tile tt = chunks {2tt, 2tt+1} = contiguous 16KB at byte tt*16384)
// w2t: [n][k] bf16 swizzled: byte(n,k) = n*256 + ((k*2) ^ ((n&7)<<4))
__global__ __launch_bounds__(256) void k0_prep(const float* __restrict__ W1,
                                               const float* __restrict__ W2,
                                               ushort* __restrict__ w1s,
                                               ushort* __restrict__ w2t)
{
    int i = blockIdx.x * 256 + threadIdx.x;
    if (i < DDIM * HDIM) {
        int t = i >> 12, rem = i & 4095;
        int n = rem >> 5, kk = rem & 31;
        int k = t * 32 + kk;
        w1s[i] = f2bf(W1[(size_t)k * HDIM + n]);
    } else if (i < DDIM * HDIM + HDIM * HDIM) {
        int j = i - DDIM * HDIM;
        int k = j >> 7, n = j & 127;
        ushort b = f2bf(W2[(size_t)k * HDIM + n]);
        size_t off = (size_t)n * 256 + (size_t)(((k * 2) ^ ((n & 7) << 4)));
        w2t[off >> 1] = b;
    }
}

// ---------------- KF: fused, 64 rows/block, BK=64, ring-2, 2 blocks/CU ----------------
// GEMM: As[2] @0 (16KB each, [64 rows][256B f32], 16B-unit swizzle ^(row&7)<<4),
//       Bs[2] @32768 (16KB each, identity copy of two w1s chunks).
// 16 tiles; per tile: vmcnt(0)+barrier, STAGE(t+1), COMPUTE(t) [stage flies over compute].
// Overlay after GEMM: Ct 16K @0; W2s 32K @16384; W1eh 3K @49152;
// stl @52224+wid*128; lossw @52736+wid*8.  Declared 65536 -> 2 blk/CU.
__global__ __launch_bounds__(256, 2) void kf_fused(
    const float* __restrict__ seq,
    const ushort* __restrict__ w1s,
    const ushort* __restrict__ w2t,
    const float* __restrict__ freq,
    const float* __restrict__ pres,
    const float* __restrict__ rmask,
    const int*   __restrict__ pidx,
    const float* __restrict__ W1,
    const float* __restrict__ b1,
    const float* __restrict__ b2,
    const float* __restrict__ W3,
    const float* __restrict__ b3,
    float* __restrict__ dec_f,
    float* __restrict__ dec_p,
    float* __restrict__ partials)
{
    __shared__ __align__(16) char lds[65536];
    const int t = threadIdx.x;
    const int wid = t >> 6, lane = t & 63;
    const int g = lane >> 4, ln = lane & 15;
    const size_t row0 = (size_t)blockIdx.x * 64;

    // A staging (BK=64, 256B rows): gload j_ covers rows j_*16 + wid*4 + (lane>>4),
    // within-row 16B unit (lane&15); source pre-swizzled so LDS holds G[row][w ^ (row&7)<<4].
    const int srow2  = wid * 4 + (lane >> 4);                      // 0..15
    const int scolb2 = ((lane & 15) * 16) ^ ((srow2 & 7) << 4);    // XOR'd source byte-in-row
    const int sldsw  = wid * 1024;                                  // wave-uniform LDS offset
    const int blane  = lane * 16;

#define STAGE(BUF, TT) do { \
    _Pragma("unroll") \
    for (int j_ = 0; j_ < 4; ++j_) { \
        const char* ga_ = (const char*)(seq + (row0 + j_ * 16 + srow2) * DDIM + (TT) * 64) + scolb2; \
        char* la_ = lds + (BUF) * 16384 + j_ * 4096 + sldsw; \
        __builtin_amdgcn_global_load_lds((const __attribute__((address_space(1))) void*)ga_, \
                                         (__attribute__((address_space(3))) void*)la_, 16, 0, 0); \
    } \
    _Pragma("unroll") \
    for (int i_ = 0; i_ < 4; ++i_) { \
        const char* gb_ = (const char*)w1s + (size_t)(TT) * 16384 + i_ * 4096 + sldsw + blane; \
        char* lb_ = lds + 32768 + (BUF) * 16384 + i_ * 4096 + sldsw; \
        __builtin_amdgcn_global_load_lds((const __attribute__((address_space(1))) void*)gb_, \
                                         (__attribute__((address_space(3))) void*)lb_, 16, 0, 0); \
    } } while (0)

#define COMPUTE(BUF) do { \
    const int p_ = wid * 16 + ln; \
    const int sw_ = (p_ & 7) << 4; \
    const char* ab_ = lds + (BUF) * 16384 + p_ * 256; \
    const ushort* bt_ = reinterpret_cast<const ushort*>(lds + 32768 + (BUF) * 16384); \
    _Pragma("unroll") \
    for (int h_ = 0; h_ < 2; ++h_) { \
        bf16x8 af; \
        f32x4 x0 = *reinterpret_cast<const f32x4*>(ab_ + ((h_ * 128 + g * 32 +  0) ^ sw_)); \
        f32x4 x1 = *reinterpret_cast<const f32x4*>(ab_ + ((h_ * 128 + g * 32 + 16) ^ sw_)); \
        af[0] = (__bf16)x0[0]; af[1] = (__bf16)x0[1]; \
        af[2] = (__bf16)x0[2]; af[3] = (__bf16)x0[3]; \
        af[4] = (__bf16)x1[0]; af[5] = (__bf16)x1[1]; \
        af[6] = (__bf16)x1[2]; af[7] = (__bf16)x1[3]; \
        const ushort* bh_ = bt_ + h_ * 4096; \
        _Pragma("unroll") \
        for (int nf_ = 0; nf_ < 8; ++nf_) { \
            bf16x8 bb = *reinterpret_cast<const bf16x8*>(bh_ + nf_ * 512 + ln * 32 + g * 8); \
            acc[nf_] = __builtin_amdgcn_mfma_f32_16x16x32_bf16(af, bb, acc[nf_], 0, 0, 0); \
        } \
    } } while (0)

#define WAITBAR0 do { \
    asm volatile("s_waitcnt vmcnt(0)" ::: "memory"); \
    __builtin_amdgcn_sched_barrier(0); \
    __builtin_amdgcn_s_barrier(); \
    __builtin_amdgcn_sched_barrier(0); } while (0)

    f32x4 acc[8];
#pragma unroll
    for (int n = 0; n < 8; ++n) acc[n] = (f32x4){0.f, 0.f, 0.f, 0.f};

    STAGE(0, 0);
    for (int tt = 0; tt < 16; ++tt) {
        WAITBAR0;                          // tile tt resident; buf[(tt+1)&1] reads done
        if (tt + 1 < 16) STAGE((tt + 1) & 1, tt + 1);   // flies across COMPUTE(tt)
        COMPUTE(tt & 1);
    }
#undef WAITBAR0
#undef COMPUTE
#undef STAGE

    __syncthreads();                   // all As/Bs reads done -> safe to alias

    // ---- C epilogue -> swizzled Ct @0: byte(row,col) = row*256 + ((col*2)^((row&7)<<4))
    {
        float b1v[8];
#pragma unroll
        for (int nf = 0; nf < 8; ++nf) b1v[nf] = b1[nf * 16 + ln];
#pragma unroll
        for (int nf = 0; nf < 8; ++nf)
#pragma unroll
            for (int r = 0; r < 4; ++r) {
                int row = wid * 16 + g * 4 + r;               // C/D map [m89]
                int colb = (nf * 32 + ln * 2) ^ ((row & 7) << 4);
                *reinterpret_cast<ushort*>(lds + row * 256 + colb) = f2bf(acc[nf][r] + b1v[nf]);
            }
    }
    // ---- stage W2s (32KB identity copy of pre-swizzled w2t) -> lds @16384
#pragma unroll
    for (int i = 0; i < 8; ++i) {
        const char* gs = (const char*)w2t + i * 4096 + sldsw + blane;
        char* ds = lds + 16384 + i * 4096 + sldsw;
        __builtin_amdgcn_global_load_lds((const __attribute__((address_space(1))) void*)gs,
                                         (__attribute__((address_space(3))) void*)ds, 16, 0, 0);
    }
    // ---- stage W1eh (12x128 bf16) @49152
    {
        ushort* W1eh = (ushort*)(lds + 49152);
        for (int i = t; i < 12 * 128; i += 256)
            W1eh[i] = f2bf(W1[(size_t)(DDIM + (i >> 7)) * HDIM + (i & 127)]);
    }
    __syncthreads();                   // Ct + W2s + W1eh ready (compiler drains cnts)

    // ======== phase B: recurrence, 16 rows per wave, W2 from LDS ========
    const char*   W2s  = lds + 16384;
    const ushort* W1eh = (const ushort*)(lds + 49152);
    float* stl   = (float*)(lds + 52224 + wid * 128);   // [16][2] wave-private
    float* lossw = (float*)(lds + 52736 + wid * 8);

    float b2v[8], w30[8], w31[8];
#pragma unroll
    for (int nf = 0; nf < 8; ++nf) {
        b2v[nf] = b2[nf * 16 + ln];
        w30[nf] = W3[(nf * 16 + ln) * 2 + 0];
        w31[nf] = W3[(nf * 16 + ln) * 2 + 1];
    }
    const float b30 = b3[0], b31 = b3[1];
    const bool owner = (ln < 4);
    float lossAcc = 0.f, maskAcc = 0.f;

    {
        const int prow = wid * 16 + ln;          // lane's h1 row (cols split by g)
        const size_t R_h = row0 + prow;
        const int pidx_h = pidx[R_h];

        float scon[32];
        {
            const int swzr = (ln & 7) << 4;      // (prow&7) = ln&7
#pragma unroll
            for (int ks = 0; ks < 4; ++ks) {
                bf16x8 v = *reinterpret_cast<const bf16x8*>(lds + prow * 256 + ((ks * 64 + g * 16) ^ swzr));
#pragma unroll
                for (int j = 0; j < 8; ++j) scon[ks * 8 + j] = (float)v[j];
            }
        }
        const int rloc = g * 4 + ln;             // owner's row (ln<4)
        const size_t R_own = row0 + wid * 16 + rloc;
        int pio = 0;
        float ffo[3] = {0,0,0}, ppo[3] = {0,0,0}, mmo[3] = {0,0,0};
        if (owner) {
            pio = pidx[R_own];
#pragma unroll
            for (int q = 0; q < 3; ++q) {
                ffo[q] = freq[R_own * 3 + q];
                ppo[q] = pres[R_own * 3 + q];
                mmo[q] = rmask[R_own * 3 + q];
            }
        }

        for (int s = 0; s < 3; ++s) {
            const int ridx_h = c_perms[pidx_h][s];
            bf16x8 afr[4];
#pragma unroll
            for (int ks = 0; ks < 4; ++ks) {
                bf16x8 ov = *reinterpret_cast<const bf16x8*>(W1eh + (9 + ridx_h) * 128 + ks * 32 + g * 8);
#pragma unroll
                for (int j = 0; j < 8; ++j)
                    afr[ks][j] = (__bf16)gelu_fast(scon[ks * 8 + j] + (float)ov[j]);
            }
            f32x4 acc2[8];
#pragma unroll
            for (int nf = 0; nf < 8; ++nf) acc2[nf] = (f32x4){0.f, 0.f, 0.f, 0.f};
            __builtin_amdgcn_s_setprio(1);       // T5: favor MFMA in mixed-phase regime
#pragma unroll
            for (int ks = 0; ks < 4; ++ks) {
#pragma unroll
                for (int nf = 0; nf < 8; ++nf) {
                    const int n = nf * 16 + ln;
                    bf16x8 bb = *reinterpret_cast<const bf16x8*>(W2s + n * 256 + ((ks * 64 + g * 16) ^ ((n & 7) << 4)));
                    acc2[nf] = __builtin_amdgcn_mfma_f32_16x16x32_bf16(afr[ks], bb, acc2[nf], 0, 0, 0);
                }
            }
            __builtin_amdgcn_s_setprio(0);
            float p0[4] = {0, 0, 0, 0}, p1[4] = {0, 0, 0, 0};
#pragma unroll
            for (int nf = 0; nf < 8; ++nf) {
#pragma unroll
                for (int r = 0; r < 4; ++r) {
                    float h2 = gelu_fast(acc2[nf][r] + b2v[nf]);
                    p0[r] += h2 * w30[nf];
                    p1[r] += h2 * w31[nf];
                }
            }
#pragma unroll
            for (int mk = 1; mk < 16; mk <<= 1) {
#pragma unroll
                for (int r = 0; r < 4; ++r) {
                    p0[r] += __shfl_xor(p0[r], mk);
                    p1[r] += __shfl_xor(p1[r], mk);
                }
            }
            if (owner) {
                const int ridx_o = c_perms[pio][s];
                float pf = ((ln == 0) ? p0[0] : (ln == 1) ? p0[1] : (ln == 2) ? p0[2] : p0[3]) + b30;
                float z  = ((ln == 0) ? p1[0] : (ln == 1) ? p1[1] : (ln == 2) ? p1[2] : p1[3]) + b31;
                float gt_f = (ridx_o == 0) ? ffo[0] : (ridx_o == 1) ? ffo[1] : ffo[2];
                float gt_p = (ridx_o == 0) ? ppo[0] : (ridx_o == 1) ? ppo[1] : ppo[2];
                float m    = (ridx_o == 0) ? mmo[0] : (ridx_o == 1) ? mmo[1] : mmo[2];
                float d = pf - gt_f;
                float pl = (fmaxf(z, 0.f) - z * gt_p + __logf(1.0f + __expf(-fabsf(z)))) * m;
                lossAcc += d * d * m + pl;
                maskAcc += m;
                bool msk = m > 0.5f;
                float act_f = msk ? pf : gt_f;
                float act_p = msk ? __builtin_amdgcn_rcpf(1.f + __expf(-z)) : gt_p;
                stl[rloc * 2 + 0] = act_f;
                stl[rloc * 2 + 1] = act_p;
                dec_f[R_own * 3 + ridx_o] = act_f;
                dec_p[R_own * 3 + ridx_o] = act_p;
            }
            if (s < 2) {                         // same-wave LDS exchange (DS in order)
                float af_ = stl[ln * 2 + 0];
                float ap_ = stl[ln * 2 + 1];
                const int c0 = g * 8;            // within-row halfword base (per ks below)
#pragma unroll
                for (int ks = 0; ks < 4; ++ks) {
                    const int cc = ks * 32 + c0;
                    bf16x8 a0 = *reinterpret_cast<const bf16x8*>(W1eh + (ridx_h * 3 + 0) * 128 + cc);
                    bf16x8 b0 = *reinterpret_cast<const bf16x8*>(W1eh + (ridx_h * 3 + 1) * 128 + cc);
                    bf16x8 c0v = *reinterpret_cast<const bf16x8*>(W1eh + (ridx_h * 3 + 2) * 128 + cc);
#pragma unroll
                    for (int j = 0; j < 8; ++j)
                        scon[ks * 8 + j] += af_ * (float)a0[j] + ap_ * (float)b0[j] + (float)c0v[j];
                }
            }
        }
    }
    // ---- wave loss reduce + block combine
#pragma unroll
    for (int mk = 1; mk < 64; mk <<= 1) {
        lossAcc += __shfl_xor(lossAcc, mk);
        maskAcc += __shfl_xor(maskAcc, mk);
    }
    if (lane == 0) { lossw[0] = lossAcc; lossw[1] = maskAcc; }
    __syncthreads();
    if (t == 0) {
        float ls = 0.f, ms = 0.f;
#pragma unroll
        for (int w = 0; w < 4; ++w) {
            const float* lw = (const float*)(lds + 52736 + w * 8);
            ls += lw[0]; ms += lw[1];
        }
        partials[2 * (size_t)blockIdx.x]     = ls;
        partials[2 * (size_t)blockIdx.x + 1] = ms;
    }
}

// ---------------- K3: deterministic final reduction ----------------
__global__ __launch_bounds__(256) void k3_reduce(const float* __restrict__ partials,
                                                 int nb, float* __restrict__ out)
{
    __shared__ float sl[256], sm[256];
    int t = threadIdx.x;
    float ls = 0.f, ms = 0.f;
    for (int i = t; i < nb; i += 256) { ls += partials[2 * i]; ms += partials[2 * i + 1]; }
    sl[t] = ls; sm[t] = ms;
    __syncthreads();
    for (int s = 128; s > 0; s >>= 1) {
        if (t < s) { sl[t] += sl[t + s]; sm[t] += sm[t + s]; }
        __syncthreads();
    }
    if (t == 0) out[0] = sl[0] / (sm[0] + 1e-8f);
}

extern "C" void kernel_launch(void* const* d_in, const int* in_sizes, int n_in,
                              void* d_out, int out_size, void* d_ws, size_t ws_size,
                              hipStream_t stream) {
    const float* seq   = (const float*)d_in[0];
    const float* freq  = (const float*)d_in[1];
    const float* pres  = (const float*)d_in[2];
    const float* rmask = (const float*)d_in[3];
    const int*   pidx  = (const int*)d_in[4];
    const float* W1    = (const float*)d_in[5];
    const float* b1    = (const float*)d_in[6];
    const float* W2    = (const float*)d_in[7];
    const float* b2    = (const float*)d_in[8];
    const float* W3    = (const float*)d_in[9];
    const float* b3    = (const float*)d_in[10];

    int B = in_sizes[4];
    float* out   = (float*)d_out;
    float* dec_f = out + 1;
    float* dec_p = out + 1 + (size_t)B * 3;

    char* ws = (char*)d_ws;
    float*  partials = (float*)ws;                        // 16 KB (2048*2*4)
    ushort* w1s  = (ushort*)(ws + 16384);                 // 256 KB
    ushort* w2t  = (ushort*)(ws + 16384 + 262144);        // 32 KB

    int nblk = B / 64;                                    // 2048
    k0_prep<<<(DDIM * HDIM + HDIM * HDIM + 255) / 256, 256, 0, stream>>>(W1, W2, w1s, w2t);
    kf_fused<<<nblk, 256, 0, stream>>>(seq, w1s, w2t, freq, pres, rmask, pidx,
                                       W1, b1, b2, W3, b3, dec_f, dec_p, partials);
    k3_reduce<<<1, 256, 0, stream>>>(partials, nblk, out);
}

// Round 18
// 174.360 us; speedup vs baseline: 1.0788x; 1.0788x over previous
//
#include <hip/hip_runtime.h>
#include <math.h>

#define DDIM 1024
#define HDIM 128

typedef float  f32x4  __attribute__((ext_vector_type(4)));
typedef __bf16 bf16x8 __attribute__((ext_vector_type(8)));

union BF2U { __bf16 h; ushort u; };

__constant__ int c_perms[6][3] = {{0,1,2},{0,2,1},{1,0,2},{1,2,0},{2,0,1},{2,1,0}};

__device__ __forceinline__ ushort f2bf(float f){
    BF2U c; c.h = (__bf16)f; return c.u;
}
// branch-free gelu: A&S 7.1.26 erf (|err| < 1.5e-7), HW exp + raw 1-ulp rcp
// (approximation is insensitive to rcp rounding; v_rcp_f32 is 1 instr vs the
//  multi-instr correctly-rounded __frcp_rn sequence)
__device__ __forceinline__ float gelu_fast(float x){
    float a = fabsf(x) * 0.70710678118654752f;
    float t = __builtin_amdgcn_rcpf(fmaf(0.3275911f, a, 1.0f));
    float p = t * fmaf(t, fmaf(t, fmaf(t, fmaf(t, 1.061405429f, -1.453152027f),
                 1.421413741f), -0.284496736f), 0.254829592f);
    float y = 1.0f - p * __expf(-a * a);
    float er = copysignf(y, x);
    return 0.5f * x * (1.0f + er);
}

// ---------------- K0: weight images (unchanged) ----------------
// w1s: 32 chunks t; halfword i = t*4096 + n*32 + kk = bf16(W1[t*32+kk][n])
// w2t: [n][k] bf16 swizzled: byte(n,k) = n*256 + ((k*2) ^ ((n&7)<<4))
__global__ __launch_bounds__(256) void k0_prep(const float* __restrict__ W1,
                                               const float* __restrict__ W2,
                                               ushort* __restrict__ w1s,
                                               ushort* __restrict__ w2t)
{
    int i = blockIdx.x * 256 + threadIdx.x;
    if (i < DDIM * HDIM) {
        int t = i >> 12, rem = i & 4095;
        int n = rem >> 5, kk = rem & 31;
        int k = t * 32 + kk;
        w1s[i] = f2bf(W1[(size_t)k * HDIM + n]);
    } else if (i < DDIM * HDIM + HDIM * HDIM) {
        int j = i - DDIM * HDIM;
        int k = j >> 7, n = j & 127;
        ushort b = f2bf(W2[(size_t)k * HDIM + n]);
        size_t off = (size_t)n * 256 + (size_t)(((k * 2) ^ ((n & 7) << 4)));
        w2t[off >> 1] = b;
    }
}

// ---------------- KF: fused, 64 rows/block, 3 blocks/CU (R15 structure) ----------------
// GEMM: As[3] @0 (24K), Bs[3] @24576 (24K), 3-ring, WAITBAR(4), cross-wave staging.
// Overlay after GEMM: Ct 16K @0; W2s 32K @16384; W1eh (bf16) 3K @49152;
// stl @52224+wid*128; lossw @52736+wid*8.  Total 52768 -> 3 blk/CU (<=53248).
__global__ __launch_bounds__(256, 3) void kf_fused(
    const float* __restrict__ seq,
    const ushort* __restrict__ w1s,
    const ushort* __restrict__ w2t,
    const float* __restrict__ freq,
    const float* __restrict__ pres,
    const float* __restrict__ rmask,
    const int*   __restrict__ pidx,
    const float* __restrict__ W1,
    const float* __restrict__ b1,
    const float* __restrict__ b2,
    const float* __restrict__ W3,
    const float* __restrict__ b3,
    float* __restrict__ dec_f,
    float* __restrict__ dec_p,
    float* __restrict__ partials)
{
    __shared__ __align__(16) char lds[52768];
    const int t = threadIdx.x;
    const int wid = t >> 6, lane = t & 63;
    const int g = lane >> 4, ln = lane & 15;
    const size_t row0 = (size_t)blockIdx.x * 64;

    const int srow  = wid * 8 + (lane >> 3);
    const int scolb = ((lane & 7) * 16) ^ ((lane >> 3) << 4);   // XOR'd source byte-in-row
    const int sldsw = wid * 1024;                                // wave-uniform LDS offset
    const int blane = lane * 16;

#define STAGE(BUF, TT) do { \
    _Pragma("unroll") \
    for (int j_ = 0; j_ < 2; ++j_) { \
        const char* ga_ = (const char*)(seq + (row0 + j_ * 32 + srow) * DDIM + (TT) * 32) + scolb; \
        char* la_ = lds + (BUF) * 8192 + j_ * 4096 + sldsw; \
        __builtin_amdgcn_global_load_lds((const __attribute__((address_space(1))) void*)ga_, \
                                         (__attribute__((address_space(3))) void*)la_, 16, 0, 0); \
    } \
    _Pragma("unroll") \
    for (int i_ = 0; i_ < 2; ++i_) { \
        const char* gb_ = (const char*)w1s + (size_t)(TT) * 8192 + i_ * 4096 + sldsw + blane; \
        char* lb_ = lds + 24576 + (BUF) * 8192 + i_ * 4096 + sldsw; \
        __builtin_amdgcn_global_load_lds((const __attribute__((address_space(1))) void*)gb_, \
                                         (__attribute__((address_space(3))) void*)lb_, 16, 0, 0); \
    } } while (0)

#define COMPUTE(BUF) do { \
    bf16x8 af; \
    { \
        const int p_ = wid * 16 + ln; \
        const int sw_ = (p_ & 7) << 4; \
        f32x4 x0 = *reinterpret_cast<const f32x4*>(lds + (BUF) * 8192 + p_ * 128 + ((g * 32 +  0) ^ sw_)); \
        f32x4 x1 = *reinterpret_cast<const f32x4*>(lds + (BUF) * 8192 + p_ * 128 + ((g * 32 + 16) ^ sw_)); \
        af[0] = (__bf16)x0[0]; af[1] = (__bf16)x0[1]; \
        af[2] = (__bf16)x0[2]; af[3] = (__bf16)x0[3]; \
        af[4] = (__bf16)x1[0]; af[5] = (__bf16)x1[1]; \
        af[6] = (__bf16)x1[2]; af[7] = (__bf16)x1[3]; \
    } \
    const ushort* btile = reinterpret_cast<const ushort*>(lds + 24576 + (BUF) * 8192); \
    _Pragma("unroll") \
    for (int nf_ = 0; nf_ < 8; ++nf_) { \
        bf16x8 bb = *reinterpret_cast<const bf16x8*>(btile + nf_ * 512 + ln * 32 + g * 8); \
        acc[nf_] = __builtin_amdgcn_mfma_f32_16x16x32_bf16(af, bb, acc[nf_], 0, 0, 0); \
    } } while (0)

#define WAITBAR(N) do { \
    asm volatile("s_waitcnt vmcnt(" #N ")" ::: "memory"); \
    __builtin_amdgcn_sched_barrier(0); \
    __builtin_amdgcn_s_barrier(); \
    __builtin_amdgcn_sched_barrier(0); } while (0)

    f32x4 acc[8];
#pragma unroll
    for (int n = 0; n < 8; ++n) acc[n] = (f32x4){0.f, 0.f, 0.f, 0.f};

    STAGE(0, 0);
    STAGE(1, 1);
    int cur = 0, nxt2 = 2;
    for (int tt = 0; tt < 30; ++tt) {
        WAITBAR(4);                    // tile tt resident across all waves
        STAGE(nxt2, tt + 2);           // overwrites tile tt-1's buf (reads proven done)
        COMPUTE(cur);
        cur  = (cur  == 2) ? 0 : cur  + 1;
        nxt2 = (nxt2 == 2) ? 0 : nxt2 + 1;
    }
    WAITBAR(4);                        // tile 30 resident (31's 4 in flight)
    COMPUTE(cur);
    cur = (cur == 2) ? 0 : cur + 1;
    WAITBAR(0);                        // tile 31 resident
    COMPUTE(cur);
#undef WAITBAR
#undef COMPUTE
#undef STAGE

    __syncthreads();                   // all As/Bs reads done -> safe to alias

    // ---- C epilogue -> swizzled Ct @0: byte(row,col) = row*256 + ((col*2)^((row&7)<<4))
    {
        float b1v[8];
#pragma unroll
        for (int nf = 0; nf < 8; ++nf) b1v[nf] = b1[nf * 16 + ln];
#pragma unroll
        for (int nf = 0; nf < 8; ++nf)
#pragma unroll
            for (int r = 0; r < 4; ++r) {
                int row = wid * 16 + g * 4 + r;               // C/D map [m89]
                int colb = (nf * 32 + ln * 2) ^ ((row & 7) << 4);
                *reinterpret_cast<ushort*>(lds + row * 256 + colb) = f2bf(acc[nf][r] + b1v[nf]);
            }
    }
    // ---- stage W2s (32KB identity copy of pre-swizzled w2t) -> lds @16384
#pragma unroll
    for (int i = 0; i < 8; ++i) {
        const char* gs = (const char*)w2t + i * 4096 + sldsw + blane;
        char* ds = lds + 16384 + i * 4096 + sldsw;
        __builtin_amdgcn_global_load_lds((const __attribute__((address_space(1))) void*)gs,
                                         (__attribute__((address_space(3))) void*)ds, 16, 0, 0);
    }
    // ---- stage W1eh (12x128 bf16) @49152
    {
        ushort* W1eh = (ushort*)(lds + 49152);
        for (int i = t; i < 12 * 128; i += 256)
            W1eh[i] = f2bf(W1[(size_t)(DDIM + (i >> 7)) * HDIM + (i & 127)]);
    }
    __syncthreads();                   // Ct + W2s + W1eh ready (compiler drains cnts)

    // ======== phase B: recurrence, 16 rows per wave, W2 from LDS ========
    const char*   W2s  = lds + 16384;
    const ushort* W1eh = (const ushort*)(lds + 49152);
    float* stl   = (float*)(lds + 52224 + wid * 128);   // [16][2] wave-private
    float* lossw = (float*)(lds + 52736 + wid * 8);

    float b2v[8], w30[8], w31[8];
#pragma unroll
    for (int nf = 0; nf < 8; ++nf) {
        b2v[nf] = b2[nf * 16 + ln];
        w30[nf] = W3[(nf * 16 + ln) * 2 + 0];
        w31[nf] = W3[(nf * 16 + ln) * 2 + 1];
    }
    const float b30 = b3[0], b31 = b3[1];
    const bool owner = (ln < 4);
    float lossAcc = 0.f, maskAcc = 0.f;

    {
        const int prow = wid * 16 + ln;          // lane's h1 row (cols split by g)
        const size_t R_h = row0 + prow;
        const int pidx_h = pidx[R_h];

        float scon[32];
        {
            const int swzr = (ln & 7) << 4;      // (prow&7) = ln&7
#pragma unroll
            for (int ks = 0; ks < 4; ++ks) {
                bf16x8 v = *reinterpret_cast<const bf16x8*>(lds + prow * 256 + ((ks * 64 + g * 16) ^ swzr));
#pragma unroll
                for (int j = 0; j < 8; ++j) scon[ks * 8 + j] = (float)v[j];
            }
        }
        const int rloc = g * 4 + ln;             // owner's row (ln<4)
        const size_t R_own = row0 + wid * 16 + rloc;
        int pio = 0;
        float ffo[3] = {0,0,0}, ppo[3] = {0,0,0}, mmo[3] = {0,0,0};
        if (owner) {
            pio = pidx[R_own];
#pragma unroll
            for (int q = 0; q < 3; ++q) {
                ffo[q] = freq[R_own * 3 + q];
                ppo[q] = pres[R_own * 3 + q];
                mmo[q] = rmask[R_own * 3 + q];
            }
        }

        for (int s = 0; s < 3; ++s) {
            const int ridx_h = c_perms[pidx_h][s];
            bf16x8 afr[4];
#pragma unroll
            for (int ks = 0; ks < 4; ++ks) {
                bf16x8 ov = *reinterpret_cast<const bf16x8*>(W1eh + (9 + ridx_h) * 128 + ks * 32 + g * 8);
#pragma unroll
                for (int j = 0; j < 8; ++j)
                    afr[ks][j] = (__bf16)gelu_fast(scon[ks * 8 + j] + (float)ov[j]);
            }
            f32x4 acc2[8];
#pragma unroll
            for (int nf = 0; nf < 8; ++nf) acc2[nf] = (f32x4){0.f, 0.f, 0.f, 0.f};
            __builtin_amdgcn_s_setprio(1);       // T5: favor MFMA in mixed-phase regime
#pragma unroll
            for (int ks = 0; ks < 4; ++ks) {
#pragma unroll
                for (int nf = 0; nf < 8; ++nf) {
                    const int n = nf * 16 + ln;
                    bf16x8 bb = *reinterpret_cast<const bf16x8*>(W2s + n * 256 + ((ks * 64 + g * 16) ^ ((n & 7) << 4)));
                    acc2[nf] = __builtin_amdgcn_mfma_f32_16x16x32_bf16(afr[ks], bb, acc2[nf], 0, 0, 0);
                }
            }
            __builtin_amdgcn_s_setprio(0);
            float p0[4] = {0, 0, 0, 0}, p1[4] = {0, 0, 0, 0};
#pragma unroll
            for (int nf = 0; nf < 8; ++nf) {
#pragma unroll
                for (int r = 0; r < 4; ++r) {
                    float h2 = gelu_fast(acc2[nf][r] + b2v[nf]);
                    p0[r] += h2 * w30[nf];
                    p1[r] += h2 * w31[nf];
                }
            }
#pragma unroll
            for (int mk = 1; mk < 16; mk <<= 1) {
#pragma unroll
                for (int r = 0; r < 4; ++r) {
                    p0[r] += __shfl_xor(p0[r], mk);
                    p1[r] += __shfl_xor(p1[r], mk);
                }
            }
            if (owner) {
                const int ridx_o = c_perms[pio][s];
                float pf = ((ln == 0) ? p0[0] : (ln == 1) ? p0[1] : (ln == 2) ? p0[2] : p0[3]) + b30;
                float z  = ((ln == 0) ? p1[0] : (ln == 1) ? p1[1] : (ln == 2) ? p1[2] : p1[3]) + b31;
                float gt_f = (ridx_o == 0) ? ffo[0] : (ridx_o == 1) ? ffo[1] : ffo[2];
                float gt_p = (ridx_o == 0) ? ppo[0] : (ridx_o == 1) ? ppo[1] : ppo[2];
                float m    = (ridx_o == 0) ? mmo[0] : (ridx_o == 1) ? mmo[1] : mmo[2];
                float d = pf - gt_f;
                float pl = (fmaxf(z, 0.f) - z * gt_p + __logf(1.0f + __expf(-fabsf(z)))) * m;
                lossAcc += d * d * m + pl;
                maskAcc += m;
                bool msk = m > 0.5f;
                float act_f = msk ? pf : gt_f;
                float act_p = msk ? __builtin_amdgcn_rcpf(1.f + __expf(-z)) : gt_p;
                stl[rloc * 2 + 0] = act_f;
                stl[rloc * 2 + 1] = act_p;
                dec_f[R_own * 3 + ridx_o] = act_f;
                dec_p[R_own * 3 + ridx_o] = act_p;
            }
            if (s < 2) {                         // same-wave LDS exchange (DS in order)
                float af_ = stl[ln * 2 + 0];
                float ap_ = stl[ln * 2 + 1];
                const int c0 = g * 8;            // within-row halfword base (per ks below)
#pragma unroll
                for (int ks = 0; ks < 4; ++ks) {
                    const int cc = ks * 32 + c0;
                    bf16x8 a0 = *reinterpret_cast<const bf16x8*>(W1eh + (ridx_h * 3 + 0) * 128 + cc);
                    bf16x8 b0 = *reinterpret_cast<const bf16x8*>(W1eh + (ridx_h * 3 + 1) * 128 + cc);
                    bf16x8 c0v = *reinterpret_cast<const bf16x8*>(W1eh + (ridx_h * 3 + 2) * 128 + cc);
#pragma unroll
                    for (int j = 0; j < 8; ++j)
                        scon[ks * 8 + j] += af_ * (float)a0[j] + ap_ * (float)b0[j] + (float)c0v[j];
                }
            }
        }
    }
    // ---- wave loss reduce + block combine
#pragma unroll
    for (int mk = 1; mk < 64; mk <<= 1) {
        lossAcc += __shfl_xor(lossAcc, mk);
        maskAcc += __shfl_xor(maskAcc, mk);
    }
    if (lane == 0) { lossw[0] = lossAcc; lossw[1] = maskAcc; }
    __syncthreads();
    if (t == 0) {
        float ls = 0.f, ms = 0.f;
#pragma unroll
        for (int w = 0; w < 4; ++w) {
            const float* lw = (const float*)(lds + 52736 + w * 8);
            ls += lw[0]; ms += lw[1];
        }
        partials[2 * (size_t)blockIdx.x]     = ls;
        partials[2 * (size_t)blockIdx.x + 1] = ms;
    }
}

// ---------------- K3: deterministic final reduction ----------------
__global__ __launch_bounds__(256) void k3_reduce(const float* __restrict__ partials,
                                                 int nb, float* __restrict__ out)
{
    __shared__ float sl[256], sm[256];
    int t = threadIdx.x;
    float ls = 0.f, ms = 0.f;
    for (int i = t; i < nb; i += 256) { ls += partials[2 * i]; ms += partials[2 * i + 1]; }
    sl[t] = ls; sm[t] = ms;
    __syncthreads();
    for (int s = 128; s > 0; s >>= 1) {
        if (t < s) { sl[t] += sl[t + s]; sm[t] += sm[t + s]; }
        __syncthreads();
    }
    if (t == 0) out[0] = sl[0] / (sm[0] + 1e-8f);
}

extern "C" void kernel_launch(void* const* d_in, const int* in_sizes, int n_in,
                              void* d_out, int out_size, void* d_ws, size_t ws_size,
                              hipStream_t stream) {
    const float* seq   = (const float*)d_in[0];
    const float* freq  = (const float*)d_in[1];
    const float* pres  = (const float*)d_in[2];
    const float* rmask = (const float*)d_in[3];
    const int*   pidx  = (const int*)d_in[4];
    const float* W1    = (const float*)d_in[5];
    const float* b1    = (const float*)d_in[6];
    const float* W2    = (const float*)d_in[7];
    const float* b2    = (const float*)d_in[8];
    const float* W3    = (const float*)d_in[9];
    const float* b3    = (const float*)d_in[10];

    int B = in_sizes[4];
    float* out   = (float*)d_out;
    float* dec_f = out + 1;
    float* dec_p = out + 1 + (size_t)B * 3;

    char* ws = (char*)d_ws;
    float*  partials = (float*)ws;                        // 16 KB (2048*2*4)
    ushort* w1s  = (ushort*)(ws + 16384);                 // 256 KB
    ushort* w2t  = (ushort*)(ws + 16384 + 262144);        // 32 KB

    int nblk = B / 64;                                    // 2048
    k0_prep<<<(DDIM * HDIM + HDIM * HDIM + 255) / 256, 256, 0, stream>>>(W1, W2, w1s, w2t);
    kf_fused<<<nblk, 256, 0, stream>>>(seq, w1s, w2t, freq, pres, rmask, pidx,
                                       W1, b1, b2, W3, b3, dec_f, dec_p, partials);
    k3_reduce<<<1, 256, 0, stream>>>(partials, nblk, out);
}